// Round 1
// baseline (1125.458 us; speedup 1.0000x reference)
//
#include <hip/hip_runtime.h>

// SparseResBlock on MI355X — round 0: correct f32 baseline.
// Pipeline: hash table -> 27-neighbor lists -> conv1 -> stats -> BN1+ReLU
//           -> conv2 (into d_out) -> stats -> BN2 + residual + ReLU (in place).

constexpr int N_VOX = 200000;
constexpr int GEXT  = 128;
constexpr int C     = 64;     // CIN == COUT
constexpr int K27   = 27;
constexpr int TBL_N = 2 * GEXT * GEXT * GEXT;  // B * G^3 = 4,194,304
constexpr float EPSF = 1e-5f;

__global__ __launch_bounds__(256) void k_fill_table(int* __restrict__ t) {
  int i = blockIdx.x * 256 + threadIdx.x;
  if (i < TBL_N) t[i] = -1;
}

__global__ __launch_bounds__(256) void k_scatter(const int* __restrict__ coords,
                                                 int* __restrict__ t) {
  int n = blockIdx.x * 256 + threadIdx.x;
  if (n >= N_VOX) return;
  int4 c = reinterpret_cast<const int4*>(coords)[n];  // (b, x, y, z)
  int lin = ((c.x * GEXT + c.y) * GEXT + c.z) * GEXT + c.w;
  t[lin] = n;
}

__global__ __launch_bounds__(256) void k_nbr(const int* __restrict__ coords,
                                             const int* __restrict__ t,
                                             int* __restrict__ nbr) {
  int n = blockIdx.x * 256 + threadIdx.x;
  if (n >= N_VOX) return;
  int4 c = reinterpret_cast<const int4*>(coords)[n];
  int k = 0;
  #pragma unroll
  for (int dx = -1; dx <= 1; ++dx)
    #pragma unroll
    for (int dy = -1; dy <= 1; ++dy)
      #pragma unroll
      for (int dz = -1; dz <= 1; ++dz) {
        int x = c.y + dx, y = c.z + dy, z = c.w + dz;
        int idx = -1;
        if (((unsigned)x < (unsigned)GEXT) & ((unsigned)y < (unsigned)GEXT) &
            ((unsigned)z < (unsigned)GEXT)) {
          int lin = ((c.x * GEXT + x) * GEXT + y) * GEXT + z;
          idx = t[lin];
        }
        nbr[k * N_VOX + n] = idx;  // -1 == invalid (out of grid or inactive)
        ++k;
      }
}

// One wave per voxel: lane = cout. feats row loads are wave-uniform
// (HW broadcast, L1-hit); w loads are coalesced 256B across the 64 lanes.
__global__ __launch_bounds__(256) void k_conv(const float* __restrict__ fin,
                                              const float* __restrict__ w,
                                              const int* __restrict__ nbr,
                                              float* __restrict__ fout) {
  int tg = blockIdx.x * 256 + threadIdx.x;   // grid sized exactly N_VOX*C
  int n  = tg >> 6;
  int cc = tg & 63;
  float acc = 0.f;
  for (int k = 0; k < K27; ++k) {
    int idx = nbr[k * N_VOX + n];            // wave-uniform
    if (idx >= 0) {
      const float* fr = fin + (size_t)idx * C;
      const float* wk = w + k * C * C + cc;
      #pragma unroll
      for (int ci = 0; ci < C; ++ci) acc = fmaf(fr[ci], wk[ci * C], acc);
    }
  }
  fout[(size_t)n * C + cc] = acc;
}

// Deterministic per-channel sum / sumsq: 256 blocks of partials, then reduce.
__global__ __launch_bounds__(256) void k_stats(const float* __restrict__ x,
                                               float* __restrict__ part) {
  __shared__ float ls[256], lss[256];
  int tid = threadIdx.x;
  int c = tid & 63, rg = tid >> 6;
  float s = 0.f, ss = 0.f;
  for (int n = blockIdx.x * 4 + rg; n < N_VOX; n += 1024) {
    float v = x[(size_t)n * C + c];
    s += v; ss += v * v;
  }
  ls[tid] = s; lss[tid] = ss;
  __syncthreads();
  if (tid < 64) {
    s  = ls[tid]  + ls[tid + 64]  + ls[tid + 128]  + ls[tid + 192];
    ss = lss[tid] + lss[tid + 64] + lss[tid + 128] + lss[tid + 192];
    part[blockIdx.x * 128 + tid]      = s;
    part[blockIdx.x * 128 + 64 + tid] = ss;
  }
}

// ab[c] = gamma*rsqrt(var+eps); ab[64+c] = beta - mean*ab[c]
__global__ __launch_bounds__(64) void k_bnfin(const float* __restrict__ part,
                                              const float* __restrict__ gamma,
                                              const float* __restrict__ beta,
                                              float* __restrict__ ab) {
  int c = threadIdx.x;
  float s = 0.f, ss = 0.f;
  for (int b = 0; b < 256; ++b) {
    s  += part[b * 128 + c];
    ss += part[b * 128 + 64 + c];
  }
  float mean = s / (float)N_VOX;
  float var  = ss / (float)N_VOX - mean * mean;
  float a = gamma[c] * rsqrtf(var + EPSF);
  ab[c]      = a;
  ab[64 + c] = beta[c] - mean * a;
}

__global__ __launch_bounds__(256) void k_bnrelu(float* __restrict__ x,
                                                const float* __restrict__ ab) {
  int i = blockIdx.x * 256 + threadIdx.x;
  int c = i & 63;
  float y = x[i] * ab[c] + ab[64 + c];
  x[i] = fmaxf(y, 0.f);
}

__global__ __launch_bounds__(256) void k_final(float* __restrict__ h2,
                                               const float* __restrict__ feats,
                                               const float* __restrict__ ab) {
  int i = blockIdx.x * 256 + threadIdx.x;
  int c = i & 63;
  float y = h2[i] * ab[c] + ab[64 + c] + feats[i];
  h2[i] = fmaxf(y, 0.f);
}

extern "C" void kernel_launch(void* const* d_in, const int* in_sizes, int n_in,
                              void* d_out, int out_size, void* d_ws, size_t ws_size,
                              hipStream_t stream) {
  const float* feats = (const float*)d_in[0];
  const float* w1    = (const float*)d_in[1];
  const float* g1    = (const float*)d_in[2];
  const float* b1    = (const float*)d_in[3];
  const float* w2    = (const float*)d_in[4];
  const float* g2    = (const float*)d_in[5];
  const float* b2    = (const float*)d_in[6];
  const int*   coords = (const int*)d_in[7];
  float* out = (float*)d_out;

  char* ws = (char*)d_ws;
  int*   table = (int*)ws;    ws += (size_t)TBL_N * 4;
  int*   nbr   = (int*)ws;    ws += (size_t)K27 * N_VOX * 4;
  float* h1    = (float*)ws;  ws += (size_t)N_VOX * C * 4;
  float* part  = (float*)ws;  ws += 256 * 128 * 4;
  float* ab1   = (float*)ws;  ws += 512;
  float* ab2   = (float*)ws;  ws += 512;

  const int ELEM_BLKS = N_VOX * C / 256;  // 50000, exact

  k_fill_table<<<(TBL_N + 255) / 256, 256, 0, stream>>>(table);
  k_scatter<<<(N_VOX + 255) / 256, 256, 0, stream>>>(coords, table);
  k_nbr<<<(N_VOX + 255) / 256, 256, 0, stream>>>(coords, table, nbr);

  k_conv<<<ELEM_BLKS, 256, 0, stream>>>(feats, w1, nbr, h1);
  k_stats<<<256, 256, 0, stream>>>(h1, part);
  k_bnfin<<<1, 64, 0, stream>>>(part, g1, b1, ab1);
  k_bnrelu<<<ELEM_BLKS, 256, 0, stream>>>(h1, ab1);

  k_conv<<<ELEM_BLKS, 256, 0, stream>>>(h1, w2, nbr, out);
  k_stats<<<256, 256, 0, stream>>>(out, part);
  k_bnfin<<<1, 64, 0, stream>>>(part, g2, b2, ab2);
  k_final<<<ELEM_BLKS, 256, 0, stream>>>(out, feats, ab2);
}

// Round 2
// 396.012 us; speedup vs baseline: 2.8420x; 2.8420x over previous
//
#include <hip/hip_runtime.h>

// SparseResBlock on MI355X — round 1: bf16 MFMA gather-GEMM convs.
// hash table -> 27-neighbor lists -> cast(feats,w) -> conv1(MFMA, bf16 out)
// -> stats -> BN1+ReLU (bf16, in place) -> conv2(MFMA, f32 -> d_out)
// -> stats -> BN2 + residual + ReLU (in place).

constexpr int N_VOX = 200000;
constexpr int GEXT  = 128;
constexpr int C     = 64;
constexpr int K27   = 27;
constexpr int TBL_N = 2 * GEXT * GEXT * GEXT;  // 4,194,304
constexpr float EPSF = 1e-5f;

using short8  = __attribute__((ext_vector_type(8))) short;
using floatx4 = __attribute__((ext_vector_type(4))) float;

static __device__ __forceinline__ ushort f2bf(float f) {
  union { float f; unsigned u; } a; a.f = f;
  unsigned r = a.u + 0x7fff + ((a.u >> 16) & 1);  // RTNE
  return (ushort)(r >> 16);
}
static __device__ __forceinline__ float bf2f(ushort h) {
  union { unsigned u; float f; } a; a.u = ((unsigned)h) << 16;
  return a.f;
}

__global__ __launch_bounds__(256) void k_fill_table(int* __restrict__ t) {
  int i = blockIdx.x * 256 + threadIdx.x;
  if (i < TBL_N) t[i] = -1;
}

__global__ __launch_bounds__(256) void k_scatter(const int* __restrict__ coords,
                                                 int* __restrict__ t) {
  int n = blockIdx.x * 256 + threadIdx.x;
  if (n >= N_VOX) return;
  int4 c = reinterpret_cast<const int4*>(coords)[n];
  int lin = ((c.x * GEXT + c.y) * GEXT + c.z) * GEXT + c.w;
  t[lin] = n;
}

__global__ __launch_bounds__(256) void k_nbr(const int* __restrict__ coords,
                                             const int* __restrict__ t,
                                             int* __restrict__ nbr) {
  int n = blockIdx.x * 256 + threadIdx.x;
  if (n >= N_VOX) return;
  int4 c = reinterpret_cast<const int4*>(coords)[n];
  int k = 0;
  #pragma unroll
  for (int dx = -1; dx <= 1; ++dx)
    #pragma unroll
    for (int dy = -1; dy <= 1; ++dy)
      #pragma unroll
      for (int dz = -1; dz <= 1; ++dz) {
        int x = c.y + dx, y = c.z + dy, z = c.w + dz;
        int idx = -1;
        if (((unsigned)x < (unsigned)GEXT) & ((unsigned)y < (unsigned)GEXT) &
            ((unsigned)z < (unsigned)GEXT)) {
          int lin = ((c.x * GEXT + x) * GEXT + y) * GEXT + z;
          idx = t[lin];
        }
        nbr[k * N_VOX + n] = idx;
        ++k;
      }
}

// f32 -> bf16, 4 elems/thread
__global__ __launch_bounds__(256) void k_cast4(const float* __restrict__ in,
                                               ushort* __restrict__ out, int n4) {
  int i = blockIdx.x * 256 + threadIdx.x;
  if (i >= n4) return;
  float4 v = reinterpret_cast<const float4*>(in)[i];
  ushort4 o;
  o.x = f2bf(v.x); o.y = f2bf(v.y); o.z = f2bf(v.z); o.w = f2bf(v.w);
  reinterpret_cast<ushort4*>(out)[i] = o;
}

// w[k][ci][co] f32 -> wt[k][co][ci] bf16
__global__ __launch_bounds__(256) void k_castw(const float* __restrict__ w,
                                               ushort* __restrict__ wt) {
  int i = blockIdx.x * 256 + threadIdx.x;
  if (i >= K27 * 4096) return;
  int k = i >> 12, r = i & 4095, co = r >> 6, ci = r & 63;
  wt[i] = f2bf(w[(k << 12) + ci * 64 + co]);
}

// MFMA gather-GEMM: block = 64 voxels x 64 cout, 4 waves (wave w: vox w*16..+16).
// A-operand = wt[k] (cout x ci), B-operand = gathered feats (ci x vox).
// D[cout][vox]; C/D layout col=lane&15 (vox), row=(lane>>4)*4+reg (cout).
template <bool OUT_BF16>
__global__ __launch_bounds__(256) void k_conv_mfma(
    const ushort* __restrict__ fb,   // [N][64] bf16
    const ushort* __restrict__ wt,   // [27][64 cout][64 ci] bf16
    const int* __restrict__ nbr,     // [27][N]
    void* __restrict__ fout) {
  __shared__ ushort As[64 * 64];     // gathered feats tile, XOR-swizzled rows
  __shared__ ushort Ws[64 * 64];     // weight tile, XOR-swizzled rows
  const int tid  = threadIdx.x;
  const int lane = tid & 63;
  const int wv   = tid >> 6;
  const int n0   = blockIdx.x * 64;

  const int srow = tid >> 3;          // staging row 0..31 (+32 on pass 2)
  const int scol = (tid & 7) * 16;    // byte offset within 128-B row

  floatx4 acc[4] = {floatx4{0.f,0.f,0.f,0.f}, floatx4{0.f,0.f,0.f,0.f},
                    floatx4{0.f,0.f,0.f,0.f}, floatx4{0.f,0.f,0.f,0.f}};

  for (int k = 0; k < K27; ++k) {
    __syncthreads();
    // stage weights (8 KB from L2)
    {
      const char* src = (const char*)(wt + (k << 12));
      #pragma unroll
      for (int p = 0; p < 2; ++p) {
        int r = srow + p * 32;
        *(float4*)((char*)Ws + r * 128 + (scol ^ ((r & 7) << 4))) =
            *(const float4*)(src + r * 128 + scol);
      }
    }
    // stage gathered feature rows (masked -> zeros)
    {
      #pragma unroll
      for (int p = 0; p < 2; ++p) {
        int r = srow + p * 32;
        int idx = nbr[k * N_VOX + n0 + r];
        float4 v = {0.f, 0.f, 0.f, 0.f};
        if (idx >= 0)
          v = *(const float4*)((const char*)fb + (size_t)idx * 128 + scol);
        *(float4*)((char*)As + r * 128 + (scol ^ ((r & 7) << 4))) = v;
      }
    }
    __syncthreads();
    // compute: K = 64 ci = 2 slices of 32
    const int arow = wv * 16 + (lane & 15);
    const int kgrp = (lane >> 4) * 16;  // byte offset of this lane's 8 bf16
    #pragma unroll
    for (int ks = 0; ks < 2; ++ks) {
      int cb = ks * 64 + kgrp;
      short8 bfrag = *(const short8*)((const char*)As + arow * 128 +
                                      (cb ^ ((arow & 7) << 4)));
      #pragma unroll
      for (int q = 0; q < 4; ++q) {
        int wrow = q * 16 + (lane & 15);
        short8 afrag = *(const short8*)((const char*)Ws + wrow * 128 +
                                        (cb ^ ((wrow & 7) << 4)));
        acc[q] = __builtin_amdgcn_mfma_f32_16x16x32_bf16(afrag, bfrag, acc[q],
                                                         0, 0, 0);
      }
    }
  }

  // epilogue: lane holds couts q*16 + (lane>>4)*4 + 0..3 for vox lane&15
  int vox   = n0 + wv * 16 + (lane & 15);
  int cbase = (lane >> 4) * 4;
  #pragma unroll
  for (int q = 0; q < 4; ++q) {
    int co = q * 16 + cbase;
    if (OUT_BF16) {
      ushort4 o;
      o.x = f2bf(acc[q][0]); o.y = f2bf(acc[q][1]);
      o.z = f2bf(acc[q][2]); o.w = f2bf(acc[q][3]);
      *(ushort4*)((ushort*)fout + (size_t)vox * C + co) = o;
    } else {
      float4 o = {acc[q][0], acc[q][1], acc[q][2], acc[q][3]};
      *(float4*)((float*)fout + (size_t)vox * C + co) = o;
    }
  }
}

// deterministic per-channel sum/sumsq partials (256 blocks), f32 and bf16 inputs
__global__ __launch_bounds__(256) void k_stats_f32(const float* __restrict__ x,
                                                   float* __restrict__ part) {
  __shared__ float ls[256], lss[256];
  int tid = threadIdx.x;
  int c = tid & 63, rg = tid >> 6;
  float s = 0.f, ss = 0.f;
  for (int n = blockIdx.x * 4 + rg; n < N_VOX; n += 1024) {
    float v = x[(size_t)n * C + c];
    s += v; ss += v * v;
  }
  ls[tid] = s; lss[tid] = ss;
  __syncthreads();
  if (tid < 64) {
    s  = ls[tid]  + ls[tid + 64]  + ls[tid + 128]  + ls[tid + 192];
    ss = lss[tid] + lss[tid + 64] + lss[tid + 128] + lss[tid + 192];
    part[blockIdx.x * 128 + tid]      = s;
    part[blockIdx.x * 128 + 64 + tid] = ss;
  }
}

__global__ __launch_bounds__(256) void k_stats_bf(const ushort* __restrict__ x,
                                                  float* __restrict__ part) {
  __shared__ float ls[256], lss[256];
  int tid = threadIdx.x;
  int c = tid & 63, rg = tid >> 6;
  float s = 0.f, ss = 0.f;
  for (int n = blockIdx.x * 4 + rg; n < N_VOX; n += 1024) {
    float v = bf2f(x[(size_t)n * C + c]);
    s += v; ss += v * v;
  }
  ls[tid] = s; lss[tid] = ss;
  __syncthreads();
  if (tid < 64) {
    s  = ls[tid]  + ls[tid + 64]  + ls[tid + 128]  + ls[tid + 192];
    ss = lss[tid] + lss[tid + 64] + lss[tid + 128] + lss[tid + 192];
    part[blockIdx.x * 128 + tid]      = s;
    part[blockIdx.x * 128 + 64 + tid] = ss;
  }
}

// ab[c] = gamma*rsqrt(var+eps); ab[64+c] = beta - mean*ab[c]
__global__ __launch_bounds__(64) void k_bnfin(const float* __restrict__ part,
                                              const float* __restrict__ gamma,
                                              const float* __restrict__ beta,
                                              float* __restrict__ ab) {
  int c = threadIdx.x;
  float s = 0.f, ss = 0.f;
  for (int b = 0; b < 256; ++b) {
    s  += part[b * 128 + c];
    ss += part[b * 128 + 64 + c];
  }
  float mean = s / (float)N_VOX;
  float var  = ss / (float)N_VOX - mean * mean;
  float a = gamma[c] * rsqrtf(var + EPSF);
  ab[c]      = a;
  ab[64 + c] = beta[c] - mean * a;
}

// BN + ReLU in place on bf16, 4 elems/thread
__global__ __launch_bounds__(256) void k_bnrelu_bf(ushort* __restrict__ x,
                                                   const float* __restrict__ ab) {
  int i = blockIdx.x * 256 + threadIdx.x;
  ushort4 v = reinterpret_cast<ushort4*>(x)[i];
  int cb = (i * 4) & 63;
  v.x = f2bf(fmaxf(bf2f(v.x) * ab[cb]     + ab[64 + cb],     0.f));
  v.y = f2bf(fmaxf(bf2f(v.y) * ab[cb + 1] + ab[64 + cb + 1], 0.f));
  v.z = f2bf(fmaxf(bf2f(v.z) * ab[cb + 2] + ab[64 + cb + 2], 0.f));
  v.w = f2bf(fmaxf(bf2f(v.w) * ab[cb + 3] + ab[64 + cb + 3], 0.f));
  reinterpret_cast<ushort4*>(x)[i] = v;
}

// BN2 + residual + ReLU in place on f32 d_out, 4 elems/thread
__global__ __launch_bounds__(256) void k_final4(float* __restrict__ h2,
                                                const float* __restrict__ feats,
                                                const float* __restrict__ ab) {
  int i = blockIdx.x * 256 + threadIdx.x;
  float4 a = reinterpret_cast<float4*>(h2)[i];
  float4 f = reinterpret_cast<const float4*>(feats)[i];
  int cb = (i * 4) & 63;
  float4 o;
  o.x = fmaxf(a.x * ab[cb]     + ab[64 + cb]     + f.x, 0.f);
  o.y = fmaxf(a.y * ab[cb + 1] + ab[64 + cb + 1] + f.y, 0.f);
  o.z = fmaxf(a.z * ab[cb + 2] + ab[64 + cb + 2] + f.z, 0.f);
  o.w = fmaxf(a.w * ab[cb + 3] + ab[64 + cb + 3] + f.w, 0.f);
  reinterpret_cast<float4*>(h2)[i] = o;
}

extern "C" void kernel_launch(void* const* d_in, const int* in_sizes, int n_in,
                              void* d_out, int out_size, void* d_ws, size_t ws_size,
                              hipStream_t stream) {
  const float* feats  = (const float*)d_in[0];
  const float* w1     = (const float*)d_in[1];
  const float* g1     = (const float*)d_in[2];
  const float* b1     = (const float*)d_in[3];
  const float* w2     = (const float*)d_in[4];
  const float* g2     = (const float*)d_in[5];
  const float* b2     = (const float*)d_in[6];
  const int*   coords = (const int*)d_in[7];
  float* out = (float*)d_out;

  char* ws = (char*)d_ws;
  int*    table = (int*)ws;     ws += (size_t)TBL_N * 4;          // 16.78 MB
  int*    nbr   = (int*)ws;     ws += (size_t)K27 * N_VOX * 4;    // 21.6 MB
  ushort* fb    = (ushort*)ws;  ws += (size_t)N_VOX * C * 2;      // 25.6 MB
  ushort* h1b   = (ushort*)ws;  ws += (size_t)N_VOX * C * 2;      // 25.6 MB
  ushort* wt1   = (ushort*)ws;  ws += (size_t)K27 * C * C * 2;
  ushort* wt2   = (ushort*)ws;  ws += (size_t)K27 * C * C * 2;
  float*  part  = (float*)ws;   ws += 256 * 128 * 4;
  float*  ab1   = (float*)ws;   ws += 512;
  float*  ab2   = (float*)ws;   ws += 512;

  const int NC4 = N_VOX * C / 4;            // 3.2M vec4 groups
  const int VBLK = NC4 / 256;               // 12500
  const int MBLK = N_VOX / 64;              // 3125

  k_fill_table<<<(TBL_N + 255) / 256, 256, 0, stream>>>(table);
  k_scatter<<<(N_VOX + 255) / 256, 256, 0, stream>>>(coords, table);
  k_nbr<<<(N_VOX + 255) / 256, 256, 0, stream>>>(coords, table, nbr);

  k_cast4<<<VBLK, 256, 0, stream>>>(feats, fb, NC4);
  k_castw<<<(K27 * 4096 + 255) / 256, 256, 0, stream>>>(w1, wt1);
  k_castw<<<(K27 * 4096 + 255) / 256, 256, 0, stream>>>(w2, wt2);

  k_conv_mfma<true><<<MBLK, 256, 0, stream>>>(fb, wt1, nbr, h1b);
  k_stats_bf<<<256, 256, 0, stream>>>(h1b, part);
  k_bnfin<<<1, 64, 0, stream>>>(part, g1, b1, ab1);
  k_bnrelu_bf<<<VBLK, 256, 0, stream>>>(h1b, ab1);

  k_conv_mfma<false><<<MBLK, 256, 0, stream>>>(h1b, wt2, nbr, out);
  k_stats_f32<<<256, 256, 0, stream>>>(out, part);
  k_bnfin<<<1, 64, 0, stream>>>(part, g2, b2, ab2);
  k_final4<<<VBLK, 256, 0, stream>>>(out, feats, ab2);
}

// Round 3
// 343.465 us; speedup vs baseline: 3.2768x; 1.1530x over previous
//
#include <hip/hip_runtime.h>

// SparseResBlock on MI355X — round 2: weights-in-LDS persistent conv with
// wave-level sparsity skip + direct per-lane global B-fragment gather.
// Stats fused into conv epilogues (deterministic per-block partials).

constexpr int N_VOX = 200000;
constexpr int GEXT  = 128;
constexpr int C     = 64;
constexpr int K27   = 27;
constexpr int TBL_N = 2 * GEXT * GEXT * GEXT;  // 4,194,304
constexpr float EPSF = 1e-5f;

constexpr int NTILE = N_VOX / 16;   // 12500 16-voxel tiles
constexpr int NBLK  = 512;          // conv grid: 256 chunks x 2 cout-halves
constexpr int WHALF = K27 * 2 * 2 * 4 * 16 * 8;  // 55296 bf16 per cout-half

using short8  = __attribute__((ext_vector_type(8))) short;
using floatx4 = __attribute__((ext_vector_type(4))) float;

static __device__ __forceinline__ ushort f2bf(float f) {
  union { float f; unsigned u; } a; a.f = f;
  unsigned r = a.u + 0x7fff + ((a.u >> 16) & 1);  // RTNE
  return (ushort)(r >> 16);
}
static __device__ __forceinline__ float bf2f(ushort h) {
  union { unsigned u; float f; } a; a.u = ((unsigned)h) << 16;
  return a.f;
}

__global__ __launch_bounds__(256) void k_fill_table(int* __restrict__ t,
                                                    ushort* __restrict__ zrow) {
  int i = blockIdx.x * 256 + threadIdx.x;
  if (i < TBL_N) t[i] = -1;
  if (i < 64) zrow[i] = 0;
}

__global__ __launch_bounds__(256) void k_scatter(const int* __restrict__ coords,
                                                 int* __restrict__ t) {
  int n = blockIdx.x * 256 + threadIdx.x;
  if (n >= N_VOX) return;
  int4 c = reinterpret_cast<const int4*>(coords)[n];
  int lin = ((c.x * GEXT + c.y) * GEXT + c.z) * GEXT + c.w;
  t[lin] = n;
}

__global__ __launch_bounds__(256) void k_nbr(const int* __restrict__ coords,
                                             const int* __restrict__ t,
                                             int* __restrict__ nbr) {
  int n = blockIdx.x * 256 + threadIdx.x;
  if (n >= N_VOX) return;
  int4 c = reinterpret_cast<const int4*>(coords)[n];
  int k = 0;
  #pragma unroll
  for (int dx = -1; dx <= 1; ++dx)
    #pragma unroll
    for (int dy = -1; dy <= 1; ++dy)
      #pragma unroll
      for (int dz = -1; dz <= 1; ++dz) {
        int x = c.y + dx, y = c.z + dy, z = c.w + dz;
        int idx = -1;
        if (((unsigned)x < (unsigned)GEXT) & ((unsigned)y < (unsigned)GEXT) &
            ((unsigned)z < (unsigned)GEXT)) {
          int lin = ((c.x * GEXT + x) * GEXT + y) * GEXT + z;
          idx = t[lin];
        }
        nbr[k * N_VOX + n] = idx;
        ++k;
      }
}

__global__ __launch_bounds__(256) void k_cast4(const float* __restrict__ in,
                                               ushort* __restrict__ out, int n4) {
  int i = blockIdx.x * 256 + threadIdx.x;
  if (i >= n4) return;
  float4 v = reinterpret_cast<const float4*>(in)[i];
  ushort4 o;
  o.x = f2bf(v.x); o.y = f2bf(v.y); o.z = f2bf(v.z); o.w = f2bf(v.w);
  reinterpret_cast<ushort4*>(out)[i] = o;
}

// w[k][ci][co] f32 -> packed bf16 [half][k][q][ks][cig][row][8]
// (A-fragment for mfma_16x16x32: lane l reads 16B at linear offset l*16)
__global__ __launch_bounds__(256) void k_castw_p(const float* __restrict__ w,
                                                 ushort* __restrict__ wtp) {
  int i = blockIdx.x * 256 + threadIdx.x;
  if (i >= K27 * 4096) return;
  int k = i >> 12, r = i & 4095, ci = r >> 6, co = r & 63;
  int half = co >> 5, q = (co >> 4) & 1, row = co & 15;
  int ks = ci >> 5, cig = (ci >> 3) & 3, e = ci & 7;
  int dst = ((((half * K27 + k) * 2 + q) * 2 + ks) * 4 + cig) * 128 + row * 8 + e;
  wtp[dst] = f2bf(w[i]);
}

// Persistent conv: block = 512 threads (8 waves), 1 block/CU (108 KB LDS).
// blockIdx: bit0 = cout-half, rest = chunk (256). Wave w handles tiles
// t = chunk*8+w, +2048, ... Each wave: 16 voxels x 32 couts, K=64.
// Per k-offset: ballot-skip, 2 global B-frag gathers/lane, 4 LDS A-frags,
// 4 MFMA. No barriers in main loop. Stats partials fused in epilogue.
template <bool OUT_BF16>
__global__ __launch_bounds__(512, 1) void k_conv_sp(
    const ushort* __restrict__ fin,   // [N][64] bf16
    const ushort* __restrict__ wtp,   // packed weights (2 halves)
    const int* __restrict__ nbr,      // [27][N]
    const ushort* __restrict__ zrow,  // 64 bf16 zeros
    void* __restrict__ fout,
    float* __restrict__ part) {       // [NBLK][64]: 32 s + 32 ss
  __shared__ ushort Wl[WHALF];        // 110592 B
  __shared__ float sred[8][4][16];

  const int tid  = threadIdx.x;
  const int lane = tid & 63;
  const int wv   = tid >> 6;
  const int half = blockIdx.x & 1;
  const int chunk = blockIdx.x >> 1;
  const int lo = lane & 15, hi = lane >> 4;

  // stage this half's weights once
  {
    const uint4* src = (const uint4*)(wtp + (size_t)half * WHALF);
    uint4* dst = (uint4*)Wl;
    for (int i = tid; i < WHALF / 8; i += 512) dst[i] = src[i];
  }
  __syncthreads();

  const char* wbase = (const char*)Wl + lane * 16;
  float s8[8], ss8[8];
  #pragma unroll
  for (int j = 0; j < 8; ++j) { s8[j] = 0.f; ss8[j] = 0.f; }

  for (int t = chunk * 8 + wv; t < NTILE; t += 2048) {
    const int n0 = t * 16;
    floatx4 acc0 = {0.f, 0.f, 0.f, 0.f};
    floatx4 acc1 = {0.f, 0.f, 0.f, 0.f};

    int idxs[27];
    #pragma unroll
    for (int k = 0; k < K27; ++k) idxs[k] = nbr[k * N_VOX + n0 + lo];

    #pragma unroll
    for (int k = 0; k < K27; ++k) {
      int idx = idxs[k];
      if (__ballot(idx >= 0)) {
        const char* base = (idx >= 0)
            ? (const char*)fin + ((size_t)idx << 7)
            : (const char*)zrow;
        short8 b0 = *(const short8*)(base + hi * 16);
        short8 b1 = *(const short8*)(base + 64 + hi * 16);
        const char* wb = wbase + k * 4096;
        short8 a00 = *(const short8*)(wb);
        short8 a01 = *(const short8*)(wb + 1024);
        short8 a10 = *(const short8*)(wb + 2048);
        short8 a11 = *(const short8*)(wb + 3072);
        acc0 = __builtin_amdgcn_mfma_f32_16x16x32_bf16(a00, b0, acc0, 0, 0, 0);
        acc0 = __builtin_amdgcn_mfma_f32_16x16x32_bf16(a01, b1, acc0, 0, 0, 0);
        acc1 = __builtin_amdgcn_mfma_f32_16x16x32_bf16(a10, b0, acc1, 0, 0, 0);
        acc1 = __builtin_amdgcn_mfma_f32_16x16x32_bf16(a11, b1, acc1, 0, 0, 0);
      }
    }

    // write outputs: lane covers vox = n0+lo, couts half*32 + {q*16 + hi*4 + r}
    const int vox = n0 + lo;
    const int cb  = half * 32 + hi * 4;
    if (OUT_BF16) {
      ushort* o = (ushort*)fout + ((size_t)vox << 6) + cb;
      ushort4 v0, v1;
      v0.x = f2bf(acc0[0]); v0.y = f2bf(acc0[1]);
      v0.z = f2bf(acc0[2]); v0.w = f2bf(acc0[3]);
      v1.x = f2bf(acc1[0]); v1.y = f2bf(acc1[1]);
      v1.z = f2bf(acc1[2]); v1.w = f2bf(acc1[3]);
      *(ushort4*)o = v0;
      *(ushort4*)(o + 16) = v1;
    } else {
      float* o = (float*)fout + ((size_t)vox << 6) + cb;
      float4 v0 = {acc0[0], acc0[1], acc0[2], acc0[3]};
      float4 v1 = {acc1[0], acc1[1], acc1[2], acc1[3]};
      *(float4*)o = v0;
      *(float4*)(o + 16) = v1;
    }
    #pragma unroll
    for (int r = 0; r < 4; ++r) {
      s8[r]     += acc0[r];  ss8[r]     += acc0[r] * acc0[r];
      s8[4 + r] += acc1[r];  ss8[4 + r] += acc1[r] * acc1[r];
    }
  }

  // reduce stats over the 16 voxel-lanes (lo); hi is preserved by xor<16
  #pragma unroll
  for (int j = 0; j < 8; ++j) {
    float s = s8[j], ss = ss8[j];
    #pragma unroll
    for (int m = 1; m < 16; m <<= 1) {
      s  += __shfl_xor(s, m);
      ss += __shfl_xor(ss, m);
    }
    if (lo == 0) { sred[wv][hi][j] = s; sred[wv][hi][8 + j] = ss; }
  }
  __syncthreads();
  if (tid < 64) {
    int h2 = tid >> 4, j = tid & 15;
    float v = 0.f;
    #pragma unroll
    for (int w = 0; w < 8; ++w) v += sred[w][h2][j];
    int j2 = j & 7;
    int c_local = ((j2 >> 2) << 4) + h2 * 4 + (j2 & 3);  // q*16 + hi*4 + r
    part[(size_t)blockIdx.x * 64 + (j < 8 ? c_local : 32 + c_local)] = v;
  }
}

// reduce partials (NBLK blocks, half-split) -> ab[c]=scale, ab[64+c]=shift
__global__ __launch_bounds__(256) void k_bnfin(const float* __restrict__ part,
                                               const float* __restrict__ gamma,
                                               const float* __restrict__ beta,
                                               float* __restrict__ ab) {
  __shared__ float red[256][2];
  int tid = threadIdx.x;
  int c = tid & 63, g = tid >> 6;
  int half = c >> 5, lc = c & 31;
  float s = 0.f, ss = 0.f;
  for (int ch = g; ch < NBLK / 2; ch += 4) {
    const float* p = part + (size_t)(ch * 2 + half) * 64;
    s += p[lc]; ss += p[32 + lc];
  }
  red[tid][0] = s; red[tid][1] = ss;
  __syncthreads();
  if (tid < 64) {
    s  = red[tid][0] + red[tid + 64][0] + red[tid + 128][0] + red[tid + 192][0];
    ss = red[tid][1] + red[tid + 64][1] + red[tid + 128][1] + red[tid + 192][1];
    float mean = s / (float)N_VOX;
    float var  = ss / (float)N_VOX - mean * mean;
    float a = gamma[tid] * rsqrtf(var + EPSF);
    ab[tid]      = a;
    ab[64 + tid] = beta[tid] - mean * a;
  }
}

__global__ __launch_bounds__(256) void k_bnrelu_bf(ushort* __restrict__ x,
                                                   const float* __restrict__ ab) {
  int i = blockIdx.x * 256 + threadIdx.x;
  ushort4 v = reinterpret_cast<ushort4*>(x)[i];
  int cb = (i * 4) & 63;
  v.x = f2bf(fmaxf(bf2f(v.x) * ab[cb]     + ab[64 + cb],     0.f));
  v.y = f2bf(fmaxf(bf2f(v.y) * ab[cb + 1] + ab[64 + cb + 1], 0.f));
  v.z = f2bf(fmaxf(bf2f(v.z) * ab[cb + 2] + ab[64 + cb + 2], 0.f));
  v.w = f2bf(fmaxf(bf2f(v.w) * ab[cb + 3] + ab[64 + cb + 3], 0.f));
  reinterpret_cast<ushort4*>(x)[i] = v;
}

// BN2 + residual(bf16 fb) + ReLU, in place on f32 d_out
__global__ __launch_bounds__(256) void k_final4(float* __restrict__ h2,
                                                const ushort* __restrict__ fb,
                                                const float* __restrict__ ab) {
  int i = blockIdx.x * 256 + threadIdx.x;
  float4 a = reinterpret_cast<float4*>(h2)[i];
  ushort4 f = reinterpret_cast<const ushort4*>(fb)[i];
  int cb = (i * 4) & 63;
  float4 o;
  o.x = fmaxf(a.x * ab[cb]     + ab[64 + cb]     + bf2f(f.x), 0.f);
  o.y = fmaxf(a.y * ab[cb + 1] + ab[64 + cb + 1] + bf2f(f.y), 0.f);
  o.z = fmaxf(a.z * ab[cb + 2] + ab[64 + cb + 2] + bf2f(f.z), 0.f);
  o.w = fmaxf(a.w * ab[cb + 3] + ab[64 + cb + 3] + bf2f(f.w), 0.f);
  reinterpret_cast<float4*>(h2)[i] = o;
}

extern "C" void kernel_launch(void* const* d_in, const int* in_sizes, int n_in,
                              void* d_out, int out_size, void* d_ws, size_t ws_size,
                              hipStream_t stream) {
  const float* feats  = (const float*)d_in[0];
  const float* w1     = (const float*)d_in[1];
  const float* g1     = (const float*)d_in[2];
  const float* b1     = (const float*)d_in[3];
  const float* w2     = (const float*)d_in[4];
  const float* g2     = (const float*)d_in[5];
  const float* b2     = (const float*)d_in[6];
  const int*   coords = (const int*)d_in[7];
  float* out = (float*)d_out;

  char* ws = (char*)d_ws;
  int*    table = (int*)ws;     ws += (size_t)TBL_N * 4;
  int*    nbr   = (int*)ws;     ws += (size_t)K27 * N_VOX * 4;
  ushort* fb    = (ushort*)ws;  ws += (size_t)N_VOX * C * 2;
  ushort* h1    = (ushort*)ws;  ws += (size_t)N_VOX * C * 2;
  ushort* wtp1  = (ushort*)ws;  ws += (size_t)2 * WHALF * 2;
  ushort* wtp2  = (ushort*)ws;  ws += (size_t)2 * WHALF * 2;
  float*  part  = (float*)ws;   ws += (size_t)NBLK * 64 * 4;
  float*  ab1   = (float*)ws;   ws += 512;
  float*  ab2   = (float*)ws;   ws += 512;
  ushort* zrow  = (ushort*)ws;  ws += 128;

  const int NC4 = N_VOX * C / 4;
  const int VBLK = NC4 / 256;   // 12500

  k_fill_table<<<(TBL_N + 255) / 256, 256, 0, stream>>>(table, zrow);
  k_scatter<<<(N_VOX + 255) / 256, 256, 0, stream>>>(coords, table);
  k_nbr<<<(N_VOX + 255) / 256, 256, 0, stream>>>(coords, table, nbr);

  k_cast4<<<VBLK, 256, 0, stream>>>(feats, fb, NC4);
  k_castw_p<<<(K27 * 4096 + 255) / 256, 256, 0, stream>>>(w1, wtp1);
  k_castw_p<<<(K27 * 4096 + 255) / 256, 256, 0, stream>>>(w2, wtp2);

  k_conv_sp<true><<<NBLK, 512, 0, stream>>>(fb, wtp1, nbr, zrow, h1, part);
  k_bnfin<<<1, 256, 0, stream>>>(part, g1, b1, ab1);
  k_bnrelu_bf<<<VBLK, 256, 0, stream>>>(h1, ab1);

  k_conv_sp<false><<<NBLK, 512, 0, stream>>>(h1, wtp2, nbr, zrow, out, part);
  k_bnfin<<<1, 256, 0, stream>>>(part, g2, b2, ab2);
  k_final4<<<VBLK, 256, 0, stream>>>(out, fb, ab2);
}